// Round 1
// baseline (774.923 us; speedup 1.0000x reference)
//
#include <hip/hip_runtime.h>

// BendingEnergy: 19-point stencil + per-batch mean reduction.
// f: (4, 160, 160, 160, 3) f32. out: (4,) f32.

#define DIM 160
#define NOUT 156               // 160 - 4
#define SX (160 * 160 * 3)     // x stride (elements)
#define SY (160 * 3)           // y stride
#define SZ 3                   // z stride

__global__ __launch_bounds__(256) void bending_energy_kernel(
    const float* __restrict__ f, float* __restrict__ out) {
    const int b = blockIdx.y;
    const long long NPTS = (long long)NOUT * NOUT * NOUT;
    long long n = (long long)blockIdx.x * blockDim.x + threadIdx.x;

    float e = 0.0f;
    if (n < NPTS) {
        int k = (int)(n % NOUT);
        int t = (int)(n / NOUT);
        int j = t % NOUT;
        int i = t / NOUT;
        int x = i + 2, y = j + 2, z = k + 2;
        const float* fb = f + (long long)b * (DIM * DIM * DIM * 3)
                            + (long long)x * SX + y * SY + z * SZ;
#pragma unroll
        for (int c = 0; c < 3; ++c) {
            const float* p = fb + c;
            float ctr = p[0];
            float dxx = 0.25f * (p[2 * SX] - 2.0f * ctr + p[-2 * SX]);
            float dyy = 0.25f * (p[2 * SY] - 2.0f * ctr + p[-2 * SY]);
            float dzz = 0.25f * (p[2 * SZ] - 2.0f * ctr + p[-2 * SZ]);
            float dxy = 0.25f * (p[SX + SY] - p[-SX + SY] - p[SX - SY] + p[-SX - SY]);
            float dxz = 0.25f * (p[SX + SZ] - p[-SX + SZ] - p[SX - SZ] + p[-SX - SZ]);
            float dyz = 0.25f * (p[SY + SZ] - p[-SY + SZ] - p[SY - SZ] + p[-SY - SZ]);
            e += dxx * dxx + dyy * dyy + dzz * dzz
               + 2.0f * (dxy * dxy + dxz * dxz + dyz * dyz);
        }
    }

    // wave-64 reduction
#pragma unroll
    for (int off = 32; off > 0; off >>= 1) e += __shfl_down(e, off, 64);

    __shared__ float ws[4];
    int lane = threadIdx.x & 63;
    int wid = threadIdx.x >> 6;
    if (lane == 0) ws[wid] = e;
    __syncthreads();
    if (threadIdx.x == 0) {
        float s = ws[0] + ws[1] + ws[2] + ws[3];
        const float inv_count = 1.0f / (156.0f * 156.0f * 156.0f * 3.0f);
        atomicAdd(&out[b], s * inv_count);
    }
}

extern "C" void kernel_launch(void* const* d_in, const int* in_sizes, int n_in,
                              void* d_out, int out_size, void* d_ws, size_t ws_size,
                              hipStream_t stream) {
    const float* f = (const float*)d_in[0];
    float* out = (float*)d_out;

    hipMemsetAsync(d_out, 0, out_size * sizeof(float), stream);

    const long long NPTS = (long long)NOUT * NOUT * NOUT;  // 3,796,416
    dim3 block(256);
    dim3 grid((unsigned)((NPTS + 255) / 256), 4);
    bending_energy_kernel<<<grid, block, 0, stream>>>(f, out);
}